// Round 20
// baseline (47.512 us; speedup 1.0000x reference)
//
#include <hip/hip_runtime.h>
#include <hip/hip_bf16.h>

// B=8192, S=200, E=8, H1=64, H2=32
// att_in = [q, h, q-h, q*h] (32) -> relu(@W1[32,64]+b1) -> relu(@W2[64,32]+b2)
// score = @W3[32,1]+b3 ; mask s<len ; out[b,:] = sum_s score*hist[b,s,:]
//
// Veff rank reduction with K-AUGMENTATION (32x32x16 MFMA), pi-permuted W1 so
// stage-1 D = stage-2 B-frags in-register (validated R17/R19). DUAL-ROW ILP.
// This round: all in-kernel bf16x2 packs via single-instruction
// v_cvt_pk_bf16_f32 (inline asm; no builtin on gfx950) replacing the 3-inst
// perm trick -> ~27% fewer VALU instructions in the hot chain.
#define BB 8192
#define SS 200

typedef __attribute__((ext_vector_type(8)))  short  short8;
typedef __attribute__((ext_vector_type(4)))  float  f32x4;
typedef __attribute__((ext_vector_type(16))) float  f32x16;

__device__ __forceinline__ unsigned short f2bf(float f) {
    union { float f; unsigned int u; } v; v.f = f;
    unsigned int r = v.u + 0x7FFFu + ((v.u >> 16) & 1u);    // RNE (prep only)
    return (unsigned short)(r >> 16);
}
// single-instruction pack: low = bf16(a), high = bf16(b), RNE.
__device__ __forceinline__ unsigned int packbf2(float a, float b) {
    unsigned int r;
    asm("v_cvt_pk_bf16_f32 %0, %1, %2" : "=v"(r) : "v"(a), "v"(b));
    return r;
}
// pi: s bits [t|b1 b0|h|r1 r0] -> [t|b1|h|b0|r1 r0]   (validated R17)
__device__ __forceinline__ int pi_perm(int s) {
    int t = s >> 5, b = (s >> 3) & 3, h = (s >> 2) & 1, r = s & 3;
    return 32 * t + 16 * (b >> 1) + 8 * h + 4 * (b & 1) + r;
}

// ---- prep ----
// wsA[t][l][j] = float2 {PA,PB}:  frag[j] = bf16(PA + q[j]*PB)
//   hi=0: PA=P1[j,i], PB=P2[j,i]   (i = pi(32t + (l&31)))
//   hi=1: PA=P0[j,i], PB=0
// wsb1p[64] = b1[pi(idx)] ; wsW2f = W2 A-frags
__global__ void prep_kernel(const float* __restrict__ W1, const float* __restrict__ W2,
                            const float* __restrict__ b1,
                            float* __restrict__ wsA, float* __restrict__ wsb1p,
                            unsigned short* __restrict__ wsW2f) {
    int tid = threadIdx.x;
    for (int e = tid; e < 1024; e += 256) {     // [t:2][l:64][j:8]
        int t = e >> 9, l = (e >> 3) & 63, j = e & 7;
        int hi = l >> 5, i = pi_perm(32 * t + (l & 31));
        float pa, pb;
        if (hi == 0) { pa = W1[(8 + j) * 64 + i] - W1[(16 + j) * 64 + i];
                       pb = W1[(24 + j) * 64 + i]; }
        else         { pa = W1[j * 64 + i] + W1[(16 + j) * 64 + i];
                       pb = 0.0f; }
        wsA[2 * e] = pa; wsA[2 * e + 1] = pb;
    }
    for (int e = tid; e < 2048; e += 256) {     // [m:4][l:64][j:8]
        int m = e >> 9, l = (e >> 3) & 63, j = e & 7;
        wsW2f[e] = f2bf(W2[(16 * m + 8 * (l >> 5) + j) * 32 + (l & 31)]);
    }
    if (tid < 64) wsb1p[tid] = b1[pi_perm(tid)];
}

// ---- main: 4 waves/block; wave owns TWO adjacent rows; 7 iters of 32 pos ----
__global__ __launch_bounds__(256)
void din14_kernel(const float* __restrict__ query,      // [B,1,8]
                  const float* __restrict__ hist,       // [B,200,8]
                  const int* __restrict__ hlen,         // [B]
                  const float* __restrict__ wsA,
                  const float* __restrict__ wsb1p,
                  const unsigned short* __restrict__ wsW2f,
                  const float* __restrict__ b2,         // [32]
                  const float* __restrict__ W3,         // [32]
                  const float* __restrict__ b3,         // [1]
                  float* __restrict__ out)              // [B,1,8]
{
    const int tid  = threadIdx.x;
    const int wave = tid >> 6;
    const int l    = tid & 63;
    const int col  = l & 31;
    const int hi   = l >> 5;
    const int wid  = blockIdx.x * 4 + wave;     // 0..4095
    const int brow0 = 2 * wid, brow1 = 2 * wid + 1;

    const int len0 = hlen[brow0], len1 = hlen[brow1];

    float q0[8], q1[8];
    {
        const float4* p = reinterpret_cast<const float4*>(query + (size_t)brow0 * 8);
        float4 a = p[0], b = p[1];
        q0[0]=a.x; q0[1]=a.y; q0[2]=a.z; q0[3]=a.w; q0[4]=b.x; q0[5]=b.y; q0[6]=b.z; q0[7]=b.w;
    }
    {
        const float4* p = reinterpret_cast<const float4*>(query + (size_t)brow1 * 8);
        float4 a = p[0], b = p[1];
        q1[0]=a.x; q1[1]=a.y; q1[2]=a.z; q1[3]=a.w; q1[4]=b.x; q1[5]=b.y; q1[6]=b.z; q1[7]=b.w;
    }

    // stage-1 A-frags per row (q-folded Veff / static P0)
    short8 a1fA[2], a1fB[2];
#pragma unroll
    for (int t = 0; t < 2; ++t) {
        const f32x4* pw = reinterpret_cast<const f32x4*>(wsA + (t * 64 + l) * 16);
        f32x4 w0 = pw[0], w1 = pw[1], w2 = pw[2], w3v = pw[3];
        union { unsigned u[4]; short8 s; } ua, ub;
        ua.u[0] = packbf2(fmaf(q0[0], w0[1], w0[0]),  fmaf(q0[1], w0[3], w0[2]));
        ua.u[1] = packbf2(fmaf(q0[2], w1[1], w1[0]),  fmaf(q0[3], w1[3], w1[2]));
        ua.u[2] = packbf2(fmaf(q0[4], w2[1], w2[0]),  fmaf(q0[5], w2[3], w2[2]));
        ua.u[3] = packbf2(fmaf(q0[6], w3v[1], w3v[0]), fmaf(q0[7], w3v[3], w3v[2]));
        ub.u[0] = packbf2(fmaf(q1[0], w0[1], w0[0]),  fmaf(q1[1], w0[3], w0[2]));
        ub.u[1] = packbf2(fmaf(q1[2], w1[1], w1[0]),  fmaf(q1[3], w1[3], w1[2]));
        ub.u[2] = packbf2(fmaf(q1[4], w2[1], w2[0]),  fmaf(q1[5], w2[3], w2[2]));
        ub.u[3] = packbf2(fmaf(q1[6], w3v[1], w3v[0]), fmaf(q1[7], w3v[3], w3v[2]));
        a1fA[t] = ua.s; a1fB[t] = ub.s;
    }

    // stage-1 B-frag constant half (q values, slots 8..15) per row
    unsigned uqcA[4] = {packbf2(q0[0], q0[1]), packbf2(q0[2], q0[3]),
                        packbf2(q0[4], q0[5]), packbf2(q0[6], q0[7])};
    unsigned uqcB[4] = {packbf2(q1[0], q1[1]), packbf2(q1[2], q1[3]),
                        packbf2(q1[4], q1[5]), packbf2(q1[6], q1[7])};

    // shared read-only C-operands: b1 (stage 1, both tiles), b2 (stage 2)
    f32x16 b1c16[2];
#pragma unroll
    for (int t = 0; t < 2; ++t)
#pragma unroll
        for (int u = 0; u < 4; ++u) {
            f32x4 v = *reinterpret_cast<const f32x4*>(wsb1p + 32 * t + 8 * u + 4 * hi);
#pragma unroll
            for (int i = 0; i < 4; ++i) b1c16[t][4 * u + i] = v[i];
        }
    f32x16 b2c16, W3v16;
#pragma unroll
    for (int u = 0; u < 4; ++u) {
        f32x4 vb = *reinterpret_cast<const f32x4*>(b2 + 8 * u + 4 * hi);
        f32x4 vw = *reinterpret_cast<const f32x4*>(W3 + 8 * u + 4 * hi);
#pragma unroll
        for (int i = 0; i < 4; ++i) { b2c16[4 * u + i] = vb[i]; W3v16[4 * u + i] = vw[i]; }
    }
    const float b3s = b3[0];

    short8 w2f[4];
#pragma unroll
    for (int m = 0; m < 4; ++m)
        w2f[m] = *reinterpret_cast<const short8*>(wsW2f + (m * 64 + l) * 8);

    const float* hrow0 = hist + (size_t)brow0 * SS * 8;
    const float* hrow1 = hist + (size_t)brow1 * SS * 8;

    float accA[8], accB[8];
#pragma unroll
    for (int e = 0; e < 8; ++e) { accA[e] = 0.0f; accB[e] = 0.0f; }

    float hA[2][8], hB[2][8];   // 2-slot rotation per row (static idx)

    auto loadH = [&](const float* hrow, int x, float* h) {
        int s = 32 * x + col;
        if (32 * x + 31 >= SS) s = min(s, SS - 1);      // folds away except x=6
        const float4* p = reinterpret_cast<const float4*>(hrow + (size_t)s * 8);
        float4 v0 = p[0], v1 = p[1];
        h[0]=v0.x; h[1]=v0.y; h[2]=v0.z; h[3]=v0.w;
        h[4]=v1.x; h[5]=v1.y; h[6]=v1.z; h[7]=v1.w;
    };

    // full per-row chain (S1 -> S2 -> score -> pool); rows are independent
    auto CH = [&](const float* h, const short8* a1f, const unsigned* uqc,
                  float* acc, int len, int x) {
        union u_s8 { unsigned u[4]; short8 s; };
        u_s8 ubf;
        ubf.u[0] = hi ? uqc[0] : packbf2(h[0], h[1]);
        ubf.u[1] = hi ? uqc[1] : packbf2(h[2], h[3]);
        ubf.u[2] = hi ? uqc[2] : packbf2(h[4], h[5]);
        ubf.u[3] = hi ? uqc[3] : packbf2(h[6], h[7]);

        f32x16 a1_0 = __builtin_amdgcn_mfma_f32_32x32x16_bf16(a1f[0], ubf.s, b1c16[0], 0, 0, 0);
        f32x16 a1_1 = __builtin_amdgcn_mfma_f32_32x32x16_bf16(a1f[1], ubf.s, b1c16[1], 0, 0, 0);

        u_s8 bB[4];
#pragma unroll
        for (int m = 0; m < 4; ++m) {
#pragma unroll
            for (int d = 0; d < 4; ++d) {
                int p0 = 8 * (m & 1) + 2 * d;
                float lo, hi2;
                if (m >> 1) { lo = a1_1[p0]; hi2 = a1_1[p0 + 1]; }
                else        { lo = a1_0[p0]; hi2 = a1_0[p0 + 1]; }
                bB[m].u[d] = packbf2(fmaxf(lo, 0.f), fmaxf(hi2, 0.f));
            }
        }

        f32x16 a2 = __builtin_amdgcn_mfma_f32_32x32x16_bf16(w2f[0], bB[0].s, b2c16, 0, 0, 0);
        a2 = __builtin_amdgcn_mfma_f32_32x32x16_bf16(w2f[1], bB[1].s, a2, 0, 0, 0);
        a2 = __builtin_amdgcn_mfma_f32_32x32x16_bf16(w2f[2], bB[2].s, a2, 0, 0, 0);
        a2 = __builtin_amdgcn_mfma_f32_32x32x16_bf16(w2f[3], bB[3].s, a2, 0, 0, 0);

        float s0 = 0.f, s1 = 0.f, s2 = 0.f, s3 = 0.f;
#pragma unroll
        for (int r = 0; r < 4; ++r) {
            s0 = fmaf(fmaxf(a2[r],      0.f), W3v16[r],      s0);
            s1 = fmaf(fmaxf(a2[4 + r],  0.f), W3v16[4 + r],  s1);
            s2 = fmaf(fmaxf(a2[8 + r],  0.f), W3v16[8 + r],  s2);
            s3 = fmaf(fmaxf(a2[12 + r], 0.f), W3v16[12 + r], s3);
        }
        float p = (s0 + s1) + (s2 + s3);
        p += __shfl_xor(p, 32);
        float sc = (32 * x + col < len) ? (p + b3s) : 0.0f;
#pragma unroll
        for (int e = 0; e < 8; ++e) acc[e] = fmaf(sc, h[e], acc[e]);
    };

    // pipeline: load(t+1) both rows | chain r0(t) | chain r1(t) — fully unrolled
    loadH(hrow0, 0, hA[0]);
    loadH(hrow1, 0, hB[0]);
#pragma unroll
    for (int it = 0; it < 7; ++it) {
        if (it + 1 < 7) {
            loadH(hrow0, it + 1, hA[(it + 1) & 1]);
            loadH(hrow1, it + 1, hB[(it + 1) & 1]);
        }
        CH(hA[it & 1], a1fA, uqcA, accA, len0, it);
        CH(hB[it & 1], a1fB, uqcB, accB, len1, it);
    }

    // reduce over the 32 position-lanes (hi-copies identical)
#pragma unroll
    for (int m = 1; m < 32; m <<= 1)
#pragma unroll
        for (int e = 0; e < 8; ++e) {
            accA[e] += __shfl_xor(accA[e], m);
            accB[e] += __shfl_xor(accB[e], m);
        }

    if (l == 0) {
        float4* op0 = reinterpret_cast<float4*>(out + (size_t)brow0 * 8);
        op0[0] = make_float4(accA[0], accA[1], accA[2], accA[3]);
        op0[1] = make_float4(accA[4], accA[5], accA[6], accA[7]);
        float4* op1 = reinterpret_cast<float4*>(out + (size_t)brow1 * 8);
        op1[0] = make_float4(accB[0], accB[1], accB[2], accB[3]);
        op1[1] = make_float4(accB[4], accB[5], accB[6], accB[7]);
    }
}

extern "C" void kernel_launch(void* const* d_in, const int* in_sizes, int n_in,
                              void* d_out, int out_size, void* d_ws, size_t ws_size,
                              hipStream_t stream) {
    const float* query = (const float*)d_in[0];
    const float* hist  = (const float*)d_in[1];
    const int*   hlen  = (const int*)d_in[2];
    const float* W1    = (const float*)d_in[3];
    const float* b1    = (const float*)d_in[4];
    const float* W2    = (const float*)d_in[5];
    const float* b2    = (const float*)d_in[6];
    const float* W3    = (const float*)d_in[7];
    const float* b3    = (const float*)d_in[8];
    float*       out   = (float*)d_out;

    char* w = (char*)d_ws;
    float*          wsA   = (float*)(w);                    // 8192 B
    float*          wsb1p = (float*)(w + 8192);             // 256 B
    unsigned short* wsW2f = (unsigned short*)(w + 8448);    // 4096 B

    prep_kernel<<<1, 256, 0, stream>>>(W1, W2, b1, wsA, wsb1p, wsW2f);
    din14_kernel<<<BB / 8, 256, 0, stream>>>(query, hist, hlen, wsA, wsb1p, wsW2f,
                                             b2, W3, b3, out);
}

// Round 21
// 38.219 us; speedup vs baseline: 1.2431x; 1.2431x over previous
//
#include <hip/hip_runtime.h>
#include <hip/hip_bf16.h>

// B=8192, S=200, E=8, H1=64, H2=32
// att_in = [q, h, q-h, q*h] (32) -> relu(@W1[32,64]+b1) -> relu(@W2[64,32]+b2)
// score = @W3[32,1]+b3 ; mask s<len ; out[b,:] = sum_s score*hist[b,s,:]
//
// CHAMPION (R19, 38.6us): Veff rank reduction with K-AUGMENTATION (32x32x16):
//   h1_i = sum_{k=0..7} Veff[k,i]*h_k + sum_{k=8..15} P0[k-8,i]*q_{k-8} + b1_i
//   hi=0 lanes carry the h half (runtime q-fold), hi=1 lanes the q half;
//   b1 rides in the shared read-only C-operand.
// pi bit-permutation on W1 columns/b1 makes stage-1 D = stage-2 B-frags
// in-register. DUAL-ROW: 2 independent row chains per wave.
// Pack = 2x v_add(0x8000) + v_perm (R13-validated); NOT inline-asm cvt_pk
// (R20: asm "v" constraints +40 VGPR -> occupancy halved -> -23%).
#define BB 8192
#define SS 200

typedef __attribute__((ext_vector_type(8)))  short  short8;
typedef __attribute__((ext_vector_type(4)))  float  f32x4;
typedef __attribute__((ext_vector_type(16))) float  f32x16;

__device__ __forceinline__ unsigned short f2bf(float f) {
    union { float f; unsigned int u; } v; v.f = f;
    unsigned int r = v.u + 0x7FFFu + ((v.u >> 16) & 1u);    // RNE (prep only)
    return (unsigned short)(r >> 16);
}
// fast pack: low = bf16(a), high = bf16(b); round-half-up (3 VALU)
__device__ __forceinline__ unsigned int packbf2(float a, float b) {
    union { float f; unsigned int u; } ua, ub;
    ua.f = a; ub.f = b;
    return __builtin_amdgcn_perm(ub.u + 0x8000u, ua.u + 0x8000u, 0x07060302u);
}
// pi: s bits [t|b1 b0|h|r1 r0] -> [t|b1|h|b0|r1 r0]   (validated R17)
__device__ __forceinline__ int pi_perm(int s) {
    int t = s >> 5, b = (s >> 3) & 3, h = (s >> 2) & 1, r = s & 3;
    return 32 * t + 16 * (b >> 1) + 8 * h + 4 * (b & 1) + r;
}

// ---- prep ----
// wsA[t][l][j] = float2 {PA,PB}:  frag[j] = bf16(PA + q[j]*PB)
//   hi=0: PA=P1[j,i], PB=P2[j,i]   (i = pi(32t + (l&31)))
//   hi=1: PA=P0[j,i], PB=0
// wsb1p[64] = b1[pi(idx)] ; wsW2f = W2 A-frags
__global__ void prep_kernel(const float* __restrict__ W1, const float* __restrict__ W2,
                            const float* __restrict__ b1,
                            float* __restrict__ wsA, float* __restrict__ wsb1p,
                            unsigned short* __restrict__ wsW2f) {
    int tid = threadIdx.x;
    for (int e = tid; e < 1024; e += 256) {     // [t:2][l:64][j:8]
        int t = e >> 9, l = (e >> 3) & 63, j = e & 7;
        int hi = l >> 5, i = pi_perm(32 * t + (l & 31));
        float pa, pb;
        if (hi == 0) { pa = W1[(8 + j) * 64 + i] - W1[(16 + j) * 64 + i];
                       pb = W1[(24 + j) * 64 + i]; }
        else         { pa = W1[j * 64 + i] + W1[(16 + j) * 64 + i];
                       pb = 0.0f; }
        wsA[2 * e] = pa; wsA[2 * e + 1] = pb;
    }
    for (int e = tid; e < 2048; e += 256) {     // [m:4][l:64][j:8]
        int m = e >> 9, l = (e >> 3) & 63, j = e & 7;
        wsW2f[e] = f2bf(W2[(16 * m + 8 * (l >> 5) + j) * 32 + (l & 31)]);
    }
    if (tid < 64) wsb1p[tid] = b1[pi_perm(tid)];
}

// ---- main: 4 waves/block; wave owns TWO adjacent rows; 7 iters of 32 pos ----
__global__ __launch_bounds__(256)
void din13_kernel(const float* __restrict__ query,      // [B,1,8]
                  const float* __restrict__ hist,       // [B,200,8]
                  const int* __restrict__ hlen,         // [B]
                  const float* __restrict__ wsA,
                  const float* __restrict__ wsb1p,
                  const unsigned short* __restrict__ wsW2f,
                  const float* __restrict__ b2,         // [32]
                  const float* __restrict__ W3,         // [32]
                  const float* __restrict__ b3,         // [1]
                  float* __restrict__ out)              // [B,1,8]
{
    const int tid  = threadIdx.x;
    const int wave = tid >> 6;
    const int l    = tid & 63;
    const int col  = l & 31;
    const int hi   = l >> 5;
    const int wid  = blockIdx.x * 4 + wave;     // 0..4095
    const int brow0 = 2 * wid, brow1 = 2 * wid + 1;

    const int len0 = hlen[brow0], len1 = hlen[brow1];

    float q0[8], q1[8];
    {
        const float4* p = reinterpret_cast<const float4*>(query + (size_t)brow0 * 8);
        float4 a = p[0], b = p[1];
        q0[0]=a.x; q0[1]=a.y; q0[2]=a.z; q0[3]=a.w; q0[4]=b.x; q0[5]=b.y; q0[6]=b.z; q0[7]=b.w;
    }
    {
        const float4* p = reinterpret_cast<const float4*>(query + (size_t)brow1 * 8);
        float4 a = p[0], b = p[1];
        q1[0]=a.x; q1[1]=a.y; q1[2]=a.z; q1[3]=a.w; q1[4]=b.x; q1[5]=b.y; q1[6]=b.z; q1[7]=b.w;
    }

    // stage-1 A-frags per row (q-folded Veff / static P0)
    short8 a1fA[2], a1fB[2];
#pragma unroll
    for (int t = 0; t < 2; ++t) {
        const f32x4* pw = reinterpret_cast<const f32x4*>(wsA + (t * 64 + l) * 16);
        f32x4 w0 = pw[0], w1 = pw[1], w2 = pw[2], w3v = pw[3];
        union { unsigned u[4]; short8 s; } ua, ub;
        ua.u[0] = packbf2(fmaf(q0[0], w0[1], w0[0]),  fmaf(q0[1], w0[3], w0[2]));
        ua.u[1] = packbf2(fmaf(q0[2], w1[1], w1[0]),  fmaf(q0[3], w1[3], w1[2]));
        ua.u[2] = packbf2(fmaf(q0[4], w2[1], w2[0]),  fmaf(q0[5], w2[3], w2[2]));
        ua.u[3] = packbf2(fmaf(q0[6], w3v[1], w3v[0]), fmaf(q0[7], w3v[3], w3v[2]));
        ub.u[0] = packbf2(fmaf(q1[0], w0[1], w0[0]),  fmaf(q1[1], w0[3], w0[2]));
        ub.u[1] = packbf2(fmaf(q1[2], w1[1], w1[0]),  fmaf(q1[3], w1[3], w1[2]));
        ub.u[2] = packbf2(fmaf(q1[4], w2[1], w2[0]),  fmaf(q1[5], w2[3], w2[2]));
        ub.u[3] = packbf2(fmaf(q1[6], w3v[1], w3v[0]), fmaf(q1[7], w3v[3], w3v[2]));
        a1fA[t] = ua.s; a1fB[t] = ub.s;
    }

    // stage-1 B-frag constant half (q values, slots 8..15) per row
    unsigned uqcA[4] = {packbf2(q0[0], q0[1]), packbf2(q0[2], q0[3]),
                        packbf2(q0[4], q0[5]), packbf2(q0[6], q0[7])};
    unsigned uqcB[4] = {packbf2(q1[0], q1[1]), packbf2(q1[2], q1[3]),
                        packbf2(q1[4], q1[5]), packbf2(q1[6], q1[7])};

    // shared read-only C-operands: b1 (stage 1, both tiles), b2 (stage 2)
    f32x16 b1c16[2];
#pragma unroll
    for (int t = 0; t < 2; ++t)
#pragma unroll
        for (int u = 0; u < 4; ++u) {
            f32x4 v = *reinterpret_cast<const f32x4*>(wsb1p + 32 * t + 8 * u + 4 * hi);
#pragma unroll
            for (int i = 0; i < 4; ++i) b1c16[t][4 * u + i] = v[i];
        }
    f32x16 b2c16, W3v16;
#pragma unroll
    for (int u = 0; u < 4; ++u) {
        f32x4 vb = *reinterpret_cast<const f32x4*>(b2 + 8 * u + 4 * hi);
        f32x4 vw = *reinterpret_cast<const f32x4*>(W3 + 8 * u + 4 * hi);
#pragma unroll
        for (int i = 0; i < 4; ++i) { b2c16[4 * u + i] = vb[i]; W3v16[4 * u + i] = vw[i]; }
    }
    const float b3s = b3[0];

    short8 w2f[4];
#pragma unroll
    for (int m = 0; m < 4; ++m)
        w2f[m] = *reinterpret_cast<const short8*>(wsW2f + (m * 64 + l) * 8);

    const float* hrow0 = hist + (size_t)brow0 * SS * 8;
    const float* hrow1 = hist + (size_t)brow1 * SS * 8;

    float accA[8], accB[8];
#pragma unroll
    for (int e = 0; e < 8; ++e) { accA[e] = 0.0f; accB[e] = 0.0f; }

    float hA[2][8], hB[2][8];   // 2-slot rotation per row (static idx)

    auto loadH = [&](const float* hrow, int x, float* h) {
        int s = 32 * x + col;
        if (32 * x + 31 >= SS) s = min(s, SS - 1);      // folds away except x=6
        const float4* p = reinterpret_cast<const float4*>(hrow + (size_t)s * 8);
        float4 v0 = p[0], v1 = p[1];
        h[0]=v0.x; h[1]=v0.y; h[2]=v0.z; h[3]=v0.w;
        h[4]=v1.x; h[5]=v1.y; h[6]=v1.z; h[7]=v1.w;
    };

    // full per-row chain (S1 -> S2 -> score -> pool); rows are independent
    auto CH = [&](const float* h, const short8* a1f, const unsigned* uqc,
                  float* acc, int len, int x) {
        union u_s8 { unsigned u[4]; short8 s; };
        u_s8 ubf;
        ubf.u[0] = hi ? uqc[0] : packbf2(h[0], h[1]);
        ubf.u[1] = hi ? uqc[1] : packbf2(h[2], h[3]);
        ubf.u[2] = hi ? uqc[2] : packbf2(h[4], h[5]);
        ubf.u[3] = hi ? uqc[3] : packbf2(h[6], h[7]);

        f32x16 a1_0 = __builtin_amdgcn_mfma_f32_32x32x16_bf16(a1f[0], ubf.s, b1c16[0], 0, 0, 0);
        f32x16 a1_1 = __builtin_amdgcn_mfma_f32_32x32x16_bf16(a1f[1], ubf.s, b1c16[1], 0, 0, 0);

        u_s8 bB[4];
#pragma unroll
        for (int m = 0; m < 4; ++m) {
#pragma unroll
            for (int d = 0; d < 4; ++d) {
                int p0 = 8 * (m & 1) + 2 * d;
                float lo, hi2;
                if (m >> 1) { lo = a1_1[p0]; hi2 = a1_1[p0 + 1]; }
                else        { lo = a1_0[p0]; hi2 = a1_0[p0 + 1]; }
                bB[m].u[d] = packbf2(fmaxf(lo, 0.f), fmaxf(hi2, 0.f));
            }
        }

        f32x16 a2 = __builtin_amdgcn_mfma_f32_32x32x16_bf16(w2f[0], bB[0].s, b2c16, 0, 0, 0);
        a2 = __builtin_amdgcn_mfma_f32_32x32x16_bf16(w2f[1], bB[1].s, a2, 0, 0, 0);
        a2 = __builtin_amdgcn_mfma_f32_32x32x16_bf16(w2f[2], bB[2].s, a2, 0, 0, 0);
        a2 = __builtin_amdgcn_mfma_f32_32x32x16_bf16(w2f[3], bB[3].s, a2, 0, 0, 0);

        float s0 = 0.f, s1 = 0.f, s2 = 0.f, s3 = 0.f;
#pragma unroll
        for (int r = 0; r < 4; ++r) {
            s0 = fmaf(fmaxf(a2[r],      0.f), W3v16[r],      s0);
            s1 = fmaf(fmaxf(a2[4 + r],  0.f), W3v16[4 + r],  s1);
            s2 = fmaf(fmaxf(a2[8 + r],  0.f), W3v16[8 + r],  s2);
            s3 = fmaf(fmaxf(a2[12 + r], 0.f), W3v16[12 + r], s3);
        }
        float p = (s0 + s1) + (s2 + s3);
        p += __shfl_xor(p, 32);
        float sc = (32 * x + col < len) ? (p + b3s) : 0.0f;
#pragma unroll
        for (int e = 0; e < 8; ++e) acc[e] = fmaf(sc, h[e], acc[e]);
    };

    // pipeline: load(t+1) both rows | chain r0(t) | chain r1(t) — fully unrolled
    loadH(hrow0, 0, hA[0]);
    loadH(hrow1, 0, hB[0]);
#pragma unroll
    for (int it = 0; it < 7; ++it) {
        if (it + 1 < 7) {
            loadH(hrow0, it + 1, hA[(it + 1) & 1]);
            loadH(hrow1, it + 1, hB[(it + 1) & 1]);
        }
        CH(hA[it & 1], a1fA, uqcA, accA, len0, it);
        CH(hB[it & 1], a1fB, uqcB, accB, len1, it);
    }

    // reduce over the 32 position-lanes (hi-copies identical)
#pragma unroll
    for (int m = 1; m < 32; m <<= 1)
#pragma unroll
        for (int e = 0; e < 8; ++e) {
            accA[e] += __shfl_xor(accA[e], m);
            accB[e] += __shfl_xor(accB[e], m);
        }

    if (l == 0) {
        float4* op0 = reinterpret_cast<float4*>(out + (size_t)brow0 * 8);
        op0[0] = make_float4(accA[0], accA[1], accA[2], accA[3]);
        op0[1] = make_float4(accA[4], accA[5], accA[6], accA[7]);
        float4* op1 = reinterpret_cast<float4*>(out + (size_t)brow1 * 8);
        op1[0] = make_float4(accB[0], accB[1], accB[2], accB[3]);
        op1[1] = make_float4(accB[4], accB[5], accB[6], accB[7]);
    }
}

extern "C" void kernel_launch(void* const* d_in, const int* in_sizes, int n_in,
                              void* d_out, int out_size, void* d_ws, size_t ws_size,
                              hipStream_t stream) {
    const float* query = (const float*)d_in[0];
    const float* hist  = (const float*)d_in[1];
    const int*   hlen  = (const int*)d_in[2];
    const float* W1    = (const float*)d_in[3];
    const float* b1    = (const float*)d_in[4];
    const float* W2    = (const float*)d_in[5];
    const float* b2    = (const float*)d_in[6];
    const float* W3    = (const float*)d_in[7];
    const float* b3    = (const float*)d_in[8];
    float*       out   = (float*)d_out;

    char* w = (char*)d_ws;
    float*          wsA   = (float*)(w);                    // 8192 B
    float*          wsb1p = (float*)(w + 8192);             // 256 B
    unsigned short* wsW2f = (unsigned short*)(w + 8448);    // 4096 B

    prep_kernel<<<1, 256, 0, stream>>>(W1, W2, b1, wsA, wsb1p, wsW2f);
    din13_kernel<<<BB / 8, 256, 0, stream>>>(query, hist, hlen, wsA, wsb1p, wsW2f,
                                             b2, W3, b3, out);
}

// Round 22
// 33.964 us; speedup vs baseline: 1.3989x; 1.1253x over previous
//
#include <hip/hip_runtime.h>
#include <hip/hip_bf16.h>

// B=8192, S=200, E=8, H1=64, H2=32
// att_in = [q, h, q-h, q*h] (32) -> relu(@W1[32,64]+b1) -> relu(@W2[64,32]+b2)
// score = @W3[32,1]+b3 ; mask s<len ; out[b,:] = sum_s score*hist[b,s,:]
//
// R19-champion structure (Veff K-augmentation, pi-permuted 32x32x16 MFMA,
// dual-row ILP, perm-trick packs) with PREP FOLDED INTO THE MAIN KERNEL:
// each wave gathers its weight fragments directly from W1/W2/b1 (L2-resident,
// setup-only) -> ONE dispatch per call instead of two (launch-overhead theory:
// dur fit = C + k*VALU with C~34us insensitive to everything else).
#define BB 8192
#define SS 200

typedef __attribute__((ext_vector_type(8)))  short  short8;
typedef __attribute__((ext_vector_type(4)))  float  f32x4;
typedef __attribute__((ext_vector_type(16))) float  f32x16;

// fast pack: low = bf16(a), high = bf16(b); round-half-up (3 VALU)
__device__ __forceinline__ unsigned int packbf2(float a, float b) {
    union { float f; unsigned int u; } ua, ub;
    ua.f = a; ub.f = b;
    return __builtin_amdgcn_perm(ub.u + 0x8000u, ua.u + 0x8000u, 0x07060302u);
}

// ---- single kernel: 4 waves/block; wave owns TWO adjacent rows; 7 iters ----
__global__ __launch_bounds__(256)
void din15_kernel(const float* __restrict__ query,      // [B,1,8]
                  const float* __restrict__ hist,       // [B,200,8]
                  const int* __restrict__ hlen,         // [B]
                  const float* __restrict__ W1,         // [32,64]
                  const float* __restrict__ b1,         // [64]
                  const float* __restrict__ W2,         // [64,32]
                  const float* __restrict__ b2,         // [32]
                  const float* __restrict__ W3,         // [32]
                  const float* __restrict__ b3,         // [1]
                  float* __restrict__ out)              // [B,1,8]
{
    const int tid  = threadIdx.x;
    const int wave = tid >> 6;
    const int l    = tid & 63;
    const int col  = l & 31;
    const int hi   = l >> 5;
    const int wid  = blockIdx.x * 4 + wave;     // 0..4095
    const int brow0 = 2 * wid, brow1 = 2 * wid + 1;

    const int len0 = hlen[brow0], len1 = hlen[brow1];

    float q0[8], q1[8];
    {
        const float4* p = reinterpret_cast<const float4*>(query + (size_t)brow0 * 8);
        float4 a = p[0], b = p[1];
        q0[0]=a.x; q0[1]=a.y; q0[2]=a.z; q0[3]=a.w; q0[4]=b.x; q0[5]=b.y; q0[6]=b.z; q0[7]=b.w;
    }
    {
        const float4* p = reinterpret_cast<const float4*>(query + (size_t)brow1 * 8);
        float4 a = p[0], b = p[1];
        q1[0]=a.x; q1[1]=a.y; q1[2]=a.z; q1[3]=a.w; q1[4]=b.x; q1[5]=b.y; q1[6]=b.z; q1[7]=b.w;
    }

    // pi(32t + col): col bits [b1 b0|h|r1 r0] -> ibase = 16*b1 + 8*h + 4*b0 + r
    const int cb = (col >> 3) & 3, chh = (col >> 2) & 1, cr = col & 3;
    const int ibase = 16 * (cb >> 1) + 8 * chh + 4 * (cb & 1) + cr;

    // stage-1 A-frags per row, gathered from W1 + q-folded:
    //   hi=0: frag[j] = bf16( (W1[8+j][i]-W1[16+j][i]) + q[j]*W1[24+j][i] )
    //   hi=1: frag[j] = bf16(  W1[j][i]+W1[16+j][i] )            (PB=0)
    short8 a1fA[2], a1fB[2];
#pragma unroll
    for (int t = 0; t < 2; ++t) {
        const int i_ = 32 * t + ibase;
        union { unsigned u[4]; short8 s; } ua, ub;
#pragma unroll
        for (int m = 0; m < 4; ++m) {
            const int j0 = 2 * m, j1 = 2 * m + 1;
            float r1a = W1[(hi ? j0 : 8 + j0) * 64 + i_];
            float r2a = W1[(16 + j0) * 64 + i_];
            float pa0 = hi ? (r1a + r2a) : (r1a - r2a);
            float pb0 = hi ? 0.0f : W1[(24 + j0) * 64 + i_];
            float r1b = W1[(hi ? j1 : 8 + j1) * 64 + i_];
            float r2b = W1[(16 + j1) * 64 + i_];
            float pa1 = hi ? (r1b + r2b) : (r1b - r2b);
            float pb1 = hi ? 0.0f : W1[(24 + j1) * 64 + i_];
            ua.u[m] = packbf2(fmaf(q0[j0], pb0, pa0), fmaf(q0[j1], pb1, pa1));
            ub.u[m] = packbf2(fmaf(q1[j0], pb0, pa0), fmaf(q1[j1], pb1, pa1));
        }
        a1fA[t] = ua.s; a1fB[t] = ub.s;
    }

    // stage-1 B-frag constant half (q values, slots 8..15) per row
    unsigned uqcA[4] = {packbf2(q0[0], q0[1]), packbf2(q0[2], q0[3]),
                        packbf2(q0[4], q0[5]), packbf2(q0[6], q0[7])};
    unsigned uqcB[4] = {packbf2(q1[0], q1[1]), packbf2(q1[2], q1[3]),
                        packbf2(q1[4], q1[5]), packbf2(q1[6], q1[7])};

    // b1 in pi-permuted D-layout: b1c16[t][4u+i] = b1[pi(32t+8u+4hi+i)]
    //   = b1[32t + 16*(u>>1) + 8*hi + 4*(u&1) + i]  -> contiguous f32x4 loads
    f32x16 b1c16[2];
#pragma unroll
    for (int t = 0; t < 2; ++t)
#pragma unroll
        for (int u = 0; u < 4; ++u) {
            f32x4 v = *reinterpret_cast<const f32x4*>(
                b1 + 32 * t + 16 * (u >> 1) + 8 * hi + 4 * (u & 1));
#pragma unroll
            for (int i = 0; i < 4; ++i) b1c16[t][4 * u + i] = v[i];
        }
    f32x16 b2c16, W3v16;
#pragma unroll
    for (int u = 0; u < 4; ++u) {
        f32x4 vb = *reinterpret_cast<const f32x4*>(b2 + 8 * u + 4 * hi);
        f32x4 vw = *reinterpret_cast<const f32x4*>(W3 + 8 * u + 4 * hi);
#pragma unroll
        for (int i = 0; i < 4; ++i) { b2c16[4 * u + i] = vb[i]; W3v16[4 * u + i] = vw[i]; }
    }
    const float b3s = b3[0];

    // stage-2 A-frags gathered from W2: w2f[m][j] = bf16(W2[16m+8hi+j][col])
    short8 w2f[4];
#pragma unroll
    for (int m = 0; m < 4; ++m) {
        union { unsigned u[4]; short8 s; } uw;
#pragma unroll
        for (int d = 0; d < 4; ++d) {
            float x0 = W2[(16 * m + 8 * hi + 2 * d)     * 32 + col];
            float x1 = W2[(16 * m + 8 * hi + 2 * d + 1) * 32 + col];
            uw.u[d] = packbf2(x0, x1);
        }
        w2f[m] = uw.s;
    }

    const float* hrow0 = hist + (size_t)brow0 * SS * 8;
    const float* hrow1 = hist + (size_t)brow1 * SS * 8;

    float accA[8], accB[8];
#pragma unroll
    for (int e = 0; e < 8; ++e) { accA[e] = 0.0f; accB[e] = 0.0f; }

    float hA[2][8], hB[2][8];   // 2-slot rotation per row (static idx)

    auto loadH = [&](const float* hrow, int x, float* h) {
        int s = 32 * x + col;
        if (32 * x + 31 >= SS) s = min(s, SS - 1);      // folds away except x=6
        const float4* p = reinterpret_cast<const float4*>(hrow + (size_t)s * 8);
        float4 v0 = p[0], v1 = p[1];
        h[0]=v0.x; h[1]=v0.y; h[2]=v0.z; h[3]=v0.w;
        h[4]=v1.x; h[5]=v1.y; h[6]=v1.z; h[7]=v1.w;
    };

    // full per-row chain (S1 -> S2 -> score -> pool); rows are independent
    auto CH = [&](const float* h, const short8* a1f, const unsigned* uqc,
                  float* acc, int len, int x) {
        union u_s8 { unsigned u[4]; short8 s; };
        u_s8 ubf;
        ubf.u[0] = hi ? uqc[0] : packbf2(h[0], h[1]);
        ubf.u[1] = hi ? uqc[1] : packbf2(h[2], h[3]);
        ubf.u[2] = hi ? uqc[2] : packbf2(h[4], h[5]);
        ubf.u[3] = hi ? uqc[3] : packbf2(h[6], h[7]);

        f32x16 a1_0 = __builtin_amdgcn_mfma_f32_32x32x16_bf16(a1f[0], ubf.s, b1c16[0], 0, 0, 0);
        f32x16 a1_1 = __builtin_amdgcn_mfma_f32_32x32x16_bf16(a1f[1], ubf.s, b1c16[1], 0, 0, 0);

        u_s8 bB[4];
#pragma unroll
        for (int m = 0; m < 4; ++m) {
#pragma unroll
            for (int d = 0; d < 4; ++d) {
                int p0 = 8 * (m & 1) + 2 * d;
                float lo, hi2;
                if (m >> 1) { lo = a1_1[p0]; hi2 = a1_1[p0 + 1]; }
                else        { lo = a1_0[p0]; hi2 = a1_0[p0 + 1]; }
                bB[m].u[d] = packbf2(fmaxf(lo, 0.f), fmaxf(hi2, 0.f));
            }
        }

        f32x16 a2 = __builtin_amdgcn_mfma_f32_32x32x16_bf16(w2f[0], bB[0].s, b2c16, 0, 0, 0);
        a2 = __builtin_amdgcn_mfma_f32_32x32x16_bf16(w2f[1], bB[1].s, a2, 0, 0, 0);
        a2 = __builtin_amdgcn_mfma_f32_32x32x16_bf16(w2f[2], bB[2].s, a2, 0, 0, 0);
        a2 = __builtin_amdgcn_mfma_f32_32x32x16_bf16(w2f[3], bB[3].s, a2, 0, 0, 0);

        float s0 = 0.f, s1 = 0.f, s2 = 0.f, s3 = 0.f;
#pragma unroll
        for (int r = 0; r < 4; ++r) {
            s0 = fmaf(fmaxf(a2[r],      0.f), W3v16[r],      s0);
            s1 = fmaf(fmaxf(a2[4 + r],  0.f), W3v16[4 + r],  s1);
            s2 = fmaf(fmaxf(a2[8 + r],  0.f), W3v16[8 + r],  s2);
            s3 = fmaf(fmaxf(a2[12 + r], 0.f), W3v16[12 + r], s3);
        }
        float p = (s0 + s1) + (s2 + s3);
        p += __shfl_xor(p, 32);
        float sc = (32 * x + col < len) ? (p + b3s) : 0.0f;
#pragma unroll
        for (int e = 0; e < 8; ++e) acc[e] = fmaf(sc, h[e], acc[e]);
    };

    // pipeline: load(t+1) both rows | chain r0(t) | chain r1(t) — fully unrolled
    loadH(hrow0, 0, hA[0]);
    loadH(hrow1, 0, hB[0]);
#pragma unroll
    for (int it = 0; it < 7; ++it) {
        if (it + 1 < 7) {
            loadH(hrow0, it + 1, hA[(it + 1) & 1]);
            loadH(hrow1, it + 1, hB[(it + 1) & 1]);
        }
        CH(hA[it & 1], a1fA, uqcA, accA, len0, it);
        CH(hB[it & 1], a1fB, uqcB, accB, len1, it);
    }

    // reduce over the 32 position-lanes (hi-copies identical)
#pragma unroll
    for (int m = 1; m < 32; m <<= 1)
#pragma unroll
        for (int e = 0; e < 8; ++e) {
            accA[e] += __shfl_xor(accA[e], m);
            accB[e] += __shfl_xor(accB[e], m);
        }

    if (l == 0) {
        float4* op0 = reinterpret_cast<float4*>(out + (size_t)brow0 * 8);
        op0[0] = make_float4(accA[0], accA[1], accA[2], accA[3]);
        op0[1] = make_float4(accA[4], accA[5], accA[6], accA[7]);
        float4* op1 = reinterpret_cast<float4*>(out + (size_t)brow1 * 8);
        op1[0] = make_float4(accB[0], accB[1], accB[2], accB[3]);
        op1[1] = make_float4(accB[4], accB[5], accB[6], accB[7]);
    }
}

extern "C" void kernel_launch(void* const* d_in, const int* in_sizes, int n_in,
                              void* d_out, int out_size, void* d_ws, size_t ws_size,
                              hipStream_t stream) {
    const float* query = (const float*)d_in[0];
    const float* hist  = (const float*)d_in[1];
    const int*   hlen  = (const int*)d_in[2];
    const float* W1    = (const float*)d_in[3];
    const float* b1    = (const float*)d_in[4];
    const float* W2    = (const float*)d_in[5];
    const float* b2    = (const float*)d_in[6];
    const float* W3    = (const float*)d_in[7];
    const float* b3    = (const float*)d_in[8];
    float*       out   = (float*)d_out;

    din15_kernel<<<BB / 8, 256, 0, stream>>>(query, hist, hlen, W1, b1, W2,
                                             b2, W3, b3, out);
}